// Round 21
// baseline (349.036 us; speedup 1.0000x reference)
//
#include <hip/hip_runtime.h>
#include <hip/hip_bf16.h>

typedef __attribute__((ext_vector_type(8))) short short8;
typedef __attribute__((ext_vector_type(4))) float floatx4;
typedef unsigned short u16;

#define D 256
#define BM 64
#define NT 256

__device__ __forceinline__ short f2bf(float f) {
    return __builtin_bit_cast(short, __float2bfloat16(f));
}

// prep: blocks [0,256): W1 fp32 [k][n] -> W1F bf16 MFMA-fragment-major:
// W1F[((k0t*16+nt)*64+lane)*8+j] = W1[k0t*32+(lane>>4)*8+j][nt*16+(lane&15)]
//       blocks [256,384): zero d_out.
__global__ void prep_kernel(const float* __restrict__ W1, u16* __restrict__ W1F,
                            float* __restrict__ out, int outn) {
    const int b = blockIdx.x;
    if (b < D) {
        const int k = b, n = threadIdx.x;
        const int k0t = k >> 5, g = (k >> 3) & 3, j = k & 7;
        const int nt = n >> 4, l15 = n & 15;
        W1F[(long)((((k0t << 4) + nt) << 6) + (g << 4) + l15) * 8 + j] = (u16)f2bf(W1[k * D + n]);
    } else {
        int i = (b - D) * 256 + threadIdx.x;
        const int stride = (gridDim.x - D) * 256;
        for (; i < outn; i += stride) out[i] = 0.f;
    }
}

struct R8 { floatx4 f0, f1; };

// Shared GEMM body (R19 structure). SCATTER=true: fused atomics (fallback).
// SCATTER=false: store per-edge scalar s to s_out (pure-stream kernel 1).
template<bool SCATTER>
__launch_bounds__(NT, 4)
__global__ void head_kernel(const float* __restrict__ forces,
                            const float* __restrict__ V_st,
                            const u16*   __restrict__ W1F,
                            const float* __restrict__ b1,
                            const float* __restrict__ W2,
                            const float* __restrict__ b2,
                            const int*   __restrict__ idx_t,
                            float* __restrict__ out,      // out array (SCATTER) 
                            float* __restrict__ s_out,    // s array (!SCATTER)
                            int E) {
    __shared__ u16 Albs[32 * 512];    // 32 KiB, fragment-major A
    __shared__ float s_red[4][BM];    // 1 KiB

    const int tid  = threadIdx.x;
    const int lane = tid & 63;
    const int wq   = tid >> 6;        // col quarter
    const int l15  = lane & 15;
    const int g    = lane >> 4;

    const long row0 = (long)blockIdx.x * BM;   // E%64==0

    float vx = 0.f, vy = 0.f, vz = 0.f;
    int node = -1;
    if (SCATTER && tid < BM) {
        long e = row0 + tid;
        vx = V_st[e * 3 + 0]; vy = V_st[e * 3 + 1]; vz = V_st[e * 3 + 2];
        node = idx_t[e];
    }

    // ---- stage A: burst 16 loads -> cvt -> fragment-major LDS ----
    const int arow = tid >> 2;
    const int agg  = tid & 3;
    const float* abase = forces + (row0 + arow) * (long)D + agg * 8;
    R8 r[8];
#pragma unroll
    for (int k0t = 0; k0t < 8; ++k0t) {
        r[k0t].f0 = *(const floatx4*)(abase + k0t * 32);
        r[k0t].f1 = *(const floatx4*)(abase + k0t * 32 + 4);
    }
    const int aslot = ((agg << 4) | (arow & 15)) * 8;
    const int art   = arow >> 4;
#pragma unroll
    for (int k0t = 0; k0t < 8; ++k0t) {
        short8 a;
#pragma unroll
        for (int j = 0; j < 4; ++j) { a[j] = f2bf(r[k0t].f0[j]); a[4 + j] = f2bf(r[k0t].f1[j]); }
        *(short8*)&Albs[(k0t * 4 + art) * 512 + aslot] = a;
    }
    __syncthreads();

    // ---- MFMA: wave = 64 rows x 64 cols (4 rt x 4 nc) ----
    floatx4 acc[4][4];
#pragma unroll
    for (int rt = 0; rt < 4; ++rt)
#pragma unroll
        for (int nc = 0; nc < 4; ++nc)
            acc[rt][nc] = (floatx4){0.f, 0.f, 0.f, 0.f};

#pragma unroll
    for (int k0t = 0; k0t < 8; ++k0t) {
        short8 bf[4], af[4];
#pragma unroll
        for (int nc = 0; nc < 4; ++nc)
            bf[nc] = *(const short8*)(W1F + (long)((k0t * 16 + wq * 4 + nc) * 64 + lane) * 8);
#pragma unroll
        for (int rt = 0; rt < 4; ++rt)
            af[rt] = *(const short8*)&Albs[(k0t * 4 + rt) * 512 + lane * 8];
#pragma unroll
        for (int rt = 0; rt < 4; ++rt)
#pragma unroll
            for (int nc = 0; nc < 4; ++nc)
                acc[rt][nc] = __builtin_amdgcn_mfma_f32_16x16x32_bf16(
                    af[rt], bf[nc], acc[rt][nc], 0, 0, 0);
    }

    // ---- epilogue: silu(z+b1) dot W2 over this wave's 64 cols ----
    float b1v[4], w2v[4];
#pragma unroll
    for (int nc = 0; nc < 4; ++nc) {
        int n = wq * 64 + nc * 16 + l15;
        b1v[nc] = b1[n];
        w2v[nc] = W2[n];
    }
    float part[4][4];
#pragma unroll
    for (int rt = 0; rt < 4; ++rt)
#pragma unroll
        for (int rr = 0; rr < 4; ++rr) {
            float sv = 0.f;
#pragma unroll
            for (int nc = 0; nc < 4; ++nc) {
                float z = acc[rt][nc][rr] + b1v[nc];
                float h = z / (1.f + __expf(-z));
                sv += h * w2v[nc];
            }
            part[rt][rr] = sv;
        }
#pragma unroll
    for (int off = 1; off < 16; off <<= 1)
#pragma unroll
        for (int rt = 0; rt < 4; ++rt)
#pragma unroll
            for (int rr = 0; rr < 4; ++rr)
                part[rt][rr] += __shfl_xor(part[rt][rr], off, 16);

    if (l15 == 0) {
#pragma unroll
        for (int rt = 0; rt < 4; ++rt)
#pragma unroll
            for (int rr = 0; rr < 4; ++rr)
                s_red[wq][rt * 16 + g * 4 + rr] = part[rt][rr];
    }
    __syncthreads();

    if (tid < BM) {
        float sv = s_red[0][tid] + s_red[1][tid] + s_red[2][tid] + s_red[3][tid] + b2[0];
        if (SCATTER) {
            if (node >= 0) {
                atomicAdd(&out[(long)node * 3 + 0], sv * vx);
                atomicAdd(&out[(long)node * 3 + 1], sv * vy);
                atomicAdd(&out[(long)node * 3 + 2], sv * vz);
            }
        } else {
            s_out[row0 + tid] = sv;   // one coalesced 256B store per block
        }
    }
}

// Kernel 2: trivial scatter. 16 MB of streams + 3 atomics/edge.
__global__ void scatter_kernel(const float* __restrict__ s,
                               const float* __restrict__ V_st,
                               const int* __restrict__ idx_t,
                               float* __restrict__ out, int E) {
    const int stride = gridDim.x * blockDim.x;
    for (int e = blockIdx.x * blockDim.x + threadIdx.x; e < E; e += stride) {
        float sv = s[e];
        long b = (long)e * 3;
        float vx = V_st[b], vy = V_st[b + 1], vz = V_st[b + 2];
        long nd = (long)idx_t[e];
        atomicAdd(&out[nd * 3 + 0], sv * vx);
        atomicAdd(&out[nd * 3 + 1], sv * vy);
        atomicAdd(&out[nd * 3 + 2], sv * vz);
    }
}

extern "C" void kernel_launch(void* const* d_in, const int* in_sizes, int n_in,
                              void* d_out, int out_size, void* d_ws, size_t ws_size,
                              hipStream_t stream) {
    const float* forces = (const float*)d_in[0];
    const float* V_st   = (const float*)d_in[1];
    const float* W1     = (const float*)d_in[2];
    const float* b1     = (const float*)d_in[3];
    const float* W2     = (const float*)d_in[4];
    const float* b2     = (const float*)d_in[5];
    const int*   idx    = (const int*)d_in[6];
    const int E = in_sizes[6];

    u16* W1F = (u16*)d_ws;                    // 128 KiB
    float* s = (float*)((char*)d_ws + 131072); // E*4 = 3.2 MB

    prep_kernel<<<D + 128, 256, 0, stream>>>(W1, W1F, (float*)d_out, out_size);
    const int grid = E / BM;
    if (ws_size >= 131072 + (size_t)E * 4) {
        // split path: pure-stream GEMM, then scatter
        head_kernel<false><<<grid, NT, 0, stream>>>(forces, V_st, W1F, b1, W2, b2,
                                                    idx, (float*)d_out, s, E);
        scatter_kernel<<<2048, 256, 0, stream>>>(s, V_st, idx, (float*)d_out, E);
    } else {
        // fallback: fused R19
        head_kernel<true><<<grid, NT, 0, stream>>>(forces, V_st, W1F, b1, W2, b2,
                                                   idx, (float*)d_out, s, E);
    }
}